// Round 1
// baseline (241.877 us; speedup 1.0000x reference)
//
#include <hip/hip_runtime.h>
#include <hip/hip_bf16.h>

// SrnmSpmm: out[b,s,n] = sum_k x[b,s,keep[k]] * values[n,k] + bias[n]
// keep[k]: cols {8i, 8i+2} of D_IN=4096 -> K=1024. M = B*S = 16384, N = 4096.
//
// Strategy R1: (1) compact+cast x -> xg bf16 [M][K] in ws, cast values -> bf16,
// (2) m97-structure 128x128 bf16 MFMA GEMM (global_load_lds w16, linear LDS),
// bias fused in epilogue. Output fp32.

#define M_TOTAL 16384
#define DIN     4096
#define KDIM    1024
#define NDIM    4096
#define BM      128
#define BN      128
#define BKT     64

typedef unsigned short u16;
typedef unsigned int   u32;
typedef __bf16 bf16x8 __attribute__((ext_vector_type(8)));
typedef float  f32x4  __attribute__((ext_vector_type(4)));

typedef const void __attribute__((address_space(1)))* gp_t;
typedef void __attribute__((address_space(3)))*       lp_t;

__device__ __forceinline__ u16 f2bf(float f) {
    u32 u = __float_as_uint(f);
    u += 0x7FFFu + ((u >> 16) & 1u);   // round-to-nearest-even
    return (u16)(u >> 16);
}

// Pass 1a: gather kept cols (0,2 of each 8-block) of x, cast to bf16.
// One thread per 8-float block: a single float4 load covers cols 0..3 (incl. 0,2).
__global__ void compact_x_kernel(const float* __restrict__ x,
                                 u32* __restrict__ xg, int nblk) {
    int i = blockIdx.x * blockDim.x + threadIdx.x;
    const int stride = gridDim.x * blockDim.x;
    for (; i < nblk; i += stride) {
        float4 v = *reinterpret_cast<const float4*>(x + (size_t)i * 8);
        xg[i] = (u32)f2bf(v.x) | ((u32)f2bf(v.z) << 16);
    }
}

// Pass 1b: cast values [N][K] fp32 -> bf16.
__global__ void conv_vals_kernel(const float* __restrict__ v,
                                 uint2* __restrict__ vb, int n4) {
    int i = blockIdx.x * blockDim.x + threadIdx.x;
    const int stride = gridDim.x * blockDim.x;
    for (; i < n4; i += stride) {
        float4 f = *reinterpret_cast<const float4*>(v + (size_t)i * 4);
        uint2 o;
        o.x = (u32)f2bf(f.x) | ((u32)f2bf(f.y) << 16);
        o.y = (u32)f2bf(f.z) | ((u32)f2bf(f.w) << 16);
        vb[i] = o;
    }
}

// Pass 2: C[M][N] = A[M][K] * Bv[N][K]^T + bias.  128x128 tile, 4 waves (2x2),
// each wave 64x64 = 4x4 MFMA 16x16x32 fragments. BK=64, single-buffered LDS,
// global_load_lds width 16 (linear LDS layout, lane-order = row-major order).
__global__ __launch_bounds__(256, 2) void gemm_kernel(
    const u16* __restrict__ A, const u16* __restrict__ Bv,
    const float* __restrict__ bias, float* __restrict__ C)
{
    __shared__ u16 As[BM * BKT];   // [128][64] linear
    __shared__ u16 Bs[BN * BKT];   // [128][64] linear

    const int tid  = threadIdx.x;
    const int lane = tid & 63;
    const int wid  = tid >> 6;
    const int wr   = wid >> 1;     // wave row 0..1 (64 rows each)
    const int wc   = wid & 1;      // wave col 0..1 (64 cols each)

    const int nbn = NDIM / BN;     // 32
    const int btm = blockIdx.x / nbn;
    const int btn = blockIdx.x % nbn;

    // staging: thread t loads 16B: row = t>>3 (+32 per iter), col elem = (t&7)*8
    const int sr = tid >> 3;
    const int sc = (tid & 7) * 8;
    const size_t a_base = (size_t)(btm * BM + sr) * KDIM + sc;
    const size_t b_base = (size_t)(btn * BN + sr) * KDIM + sc;

    // MFMA fragment addressing (16x16x32 bf16):
    //   A: row = lane&15, k = (lane>>4)*8 + j     (8 contiguous K elems = 16B)
    //   B: col = lane&15, k = (lane>>4)*8 + j
    //   C/D: col = lane&15, row = (lane>>4)*4 + j
    const int lrow = lane & 15;
    const int lko  = (lane >> 4) * 8;

    f32x4 acc[4][4] = {};

    for (int k0 = 0; k0 < KDIM; k0 += BKT) {
#pragma unroll
        for (int it = 0; it < 4; ++it) {
            __builtin_amdgcn_global_load_lds(
                (gp_t)(A + a_base + (size_t)it * 32 * KDIM + k0),
                (lp_t)(&As[it * 2048 + tid * 8]), 16, 0, 0);
            __builtin_amdgcn_global_load_lds(
                (gp_t)(Bv + b_base + (size_t)it * 32 * KDIM + k0),
                (lp_t)(&Bs[it * 2048 + tid * 8]), 16, 0, 0);
        }
        __syncthreads();   // compiler emits vmcnt(0) drain before barrier

#pragma unroll
        for (int kk = 0; kk < BKT; kk += 32) {
            bf16x8 af[4], bfr[4];
#pragma unroll
            for (int m = 0; m < 4; ++m)
                af[m] = *reinterpret_cast<const bf16x8*>(
                    &As[(wr * 64 + m * 16 + lrow) * BKT + kk + lko]);
#pragma unroll
            for (int n = 0; n < 4; ++n)
                bfr[n] = *reinterpret_cast<const bf16x8*>(
                    &Bs[(wc * 64 + n * 16 + lrow) * BKT + kk + lko]);
#pragma unroll
            for (int m = 0; m < 4; ++m)
#pragma unroll
                for (int n = 0; n < 4; ++n)
                    acc[m][n] = __builtin_amdgcn_mfma_f32_16x16x32_bf16(
                        af[m], bfr[n], acc[m][n], 0, 0, 0);
        }
        __syncthreads();
    }

    // Epilogue: bias add + fp32 store.
    const int row_base = btm * BM + wr * 64 + (lane >> 4) * 4;
    const int col_base = btn * BN + wc * 64 + lrow;
#pragma unroll
    for (int n = 0; n < 4; ++n) {
        const int col = col_base + n * 16;
        const float bv = bias[col];
#pragma unroll
        for (int m = 0; m < 4; ++m) {
            const int row = row_base + m * 16;
            f32x4 a = acc[m][n];
#pragma unroll
            for (int j = 0; j < 4; ++j)
                C[(size_t)(row + j) * NDIM + col] = a[j] + bv;
        }
    }
}

extern "C" void kernel_launch(void* const* d_in, const int* in_sizes, int n_in,
                              void* d_out, int out_size, void* d_ws, size_t ws_size,
                              hipStream_t stream) {
    const float* x      = (const float*)d_in[0];
    const float* values = (const float*)d_in[1];
    const float* bias   = (const float*)d_in[2];
    float* out = (float*)d_out;

    // ws layout: xg bf16 [16384][1024] = 32MB @ 0; values bf16 [4096][1024] = 8MB @ 32MB
    u16* xg = (u16*)d_ws;
    u16* vb = (u16*)((char*)d_ws + ((size_t)32 << 20));

    const int nblk = M_TOTAL * (DIN / 8);        // 8,388,608
    compact_x_kernel<<<2048, 256, 0, stream>>>(x, (u32*)xg, nblk);

    const int n4 = NDIM * KDIM / 4;              // 1,048,576
    conv_vals_kernel<<<1024, 256, 0, stream>>>(values, (uint2*)vb, n4);

    const int grid = (M_TOTAL / BM) * (NDIM / BN);  // 4096
    gemm_kernel<<<grid, 256, 0, stream>>>(xg, vb, bias, out);
}